// Round 8
// baseline (144.587 us; speedup 1.0000x reference)
//
#include <hip/hip_runtime.h>

// MHA b=2 n=2048 c=1024 h=16 d=64. bf16 MFMA everywhere, f32 accum.
// R8: f32->bf16 conversion FUSED into Q/K/V projections (reg-staged A with
//     cvt_pk; B via global_load_lds from pre-converted bf16 weights).
//     cvt kernel now converts only the 4 weight matrices. attn = R7 verbatim.
// ws: [0,8M) AO bf16 | [8M,16M) Vt bf16 | [24M,32M) w*b bf16 | [32M,40M) Qh
//     | [40M,48M) Kh.

typedef float f32x4 __attribute__((ext_vector_type(4)));
typedef float f32x16 __attribute__((ext_vector_type(16)));
typedef __bf16 bf16x8 __attribute__((ext_vector_type(8)));

#define SEQ 2048
#define CH 1024
#define NH 16
#define HD 64
#define TOK 4096
// 0.125 (d^-1/2) * log2(e): fold softmax base-2 conversion into Q
#define QSCALE 0.18033688011112042f

__device__ __forceinline__ unsigned short f2b(float f) {
  unsigned int u = __float_as_uint(f);
  u = (u + 0x7FFFu + ((u >> 16) & 1u)) >> 16;  // RNE
  return (unsigned short)u;
}

__device__ __forceinline__ float fexp2(float x) {  // guaranteed single v_exp_f32
  float r;
  asm("v_exp_f32 %0, %1" : "=v"(r) : "v"(x));
  return r;
}

__device__ __forceinline__ unsigned int cvtpk(float lo, float hi) {
  unsigned int r;
  asm("v_cvt_pk_bf16_f32 %0, %1, %2" : "=v"(r) : "v"(lo), "v"(hi));
  return r;
}

__device__ __forceinline__ void gload16(const void* g, void* l) {
  __builtin_amdgcn_global_load_lds(
      (const __attribute__((address_space(1))) unsigned int*)g,
      (__attribute__((address_space(3))) unsigned int*)l, 16, 0, 0);
}

// ---------------- f32 -> bf16 conversion (weights only) ----------------
struct CvtArgs {
  const float* src[4];
  unsigned short* dst[4];
  int n4[4];
};

__global__ __launch_bounds__(256) void cvt_kernel(CvtArgs a) {
  const int s = blockIdx.y;
  const int n4 = a.n4[s];
  const float4* __restrict__ src = (const float4*)a.src[s];
  unsigned short* __restrict__ dst = a.dst[s];
  const int stride = gridDim.x * blockDim.x;
  for (int i = blockIdx.x * blockDim.x + threadIdx.x; i < n4; i += stride) {
    float4 w = src[i];
    ushort4 o;
    o.x = f2b(w.x); o.y = f2b(w.y); o.z = f2b(w.z); o.w = f2b(w.w);
    *(ushort4*)(dst + 4 * (size_t)i) = o;
  }
}

// ---------------- fused-cvt GEMM: Xf32[4096,1024] @ W^T + bias --------------
// 128x64 tile, BK=32, 3 LDS buffers. A (X) reg-staged f32->bf16; B gload_lds.
// mode 0: bf16 head layout [bh][n][d] scaled by QSCALE (Q)
// mode 1: bf16 head layout (K)
// mode 3: bf16 transposed head layout [bh][d][n] (V^T)
struct Proj3Args {
  const float* X[3];
  const unsigned short* W[3];
  const float* bias[3];
  unsigned short* outb[3];
  int mode[3];
};

__global__ __launch_bounds__(256, 4) void proj3_kernel(Proj3Args a) {
  constexpr int BUFB = 8192 + 4096;  // A(128x32 bf16) + B(64x32 bf16)
  __shared__ __align__(16) unsigned char smem[3 * BUFB];
  const int z = blockIdx.z;
  const float* __restrict__ X = a.X[z];
  const unsigned short* __restrict__ W = a.W[z];
  const float* __restrict__ bias = a.bias[z];
  unsigned short* __restrict__ outb = a.outb[z];
  const int mode = a.mode[z];
  const int tid = threadIdx.x, wid = tid >> 6, lane = tid & 63;
  const int wm = wid >> 1, wn = wid & 1;
  const int mt = blockIdx.x, nt = blockIdx.y;
  const int l15 = lane & 15, l4 = lane >> 4;

  // per-thread source bases
  const float* Asrc = X + (size_t)(mt * 128 + (tid >> 1)) * CH + (tid & 1) * 16;
  const unsigned short* Bsrc = W + (size_t)(nt * 64 + (tid >> 2)) * CH + (tid & 3) * 8;
  unsigned char* const Adst0 = smem + tid * 32;          // + buf*BUFB
  unsigned char* const Bdst0 = smem + 8192 + tid * 16;   // + buf*BUFB

  // bias loads pinned before any staging (retire before in-loop vmcnt counts)
  float bvv[2];
#pragma unroll
  for (int nj = 0; nj < 2; ++nj)
    bvv[nj] = bias[nt * 64 + wn * 32 + nj * 16 + l15];

  f32x4 acc[4][2] = {};
  float4 a0[4], a1[4];  // two parity sets of A f32 regs (tile t -> set t&1)

#define LOADA(SET, T)                                                        \
  {                                                                          \
    _Pragma("unroll") for (int j = 0; j < 4; ++j)                            \
        SET[j] = *(const float4*)(Asrc + (T) * 32 + 4 * j);                  \
  }
#define DMAB(T) gload16(Bsrc + (T) * 32, Bdst0 + ((T) % 3) * BUFB);
#define WRITEA(SET, T)                                                       \
  {                                                                          \
    unsigned int pk[8];                                                      \
    _Pragma("unroll") for (int j = 0; j < 4; ++j) {                          \
      pk[2 * j] = cvtpk(SET[j].x, SET[j].y);                                 \
      pk[2 * j + 1] = cvtpk(SET[j].z, SET[j].w);                             \
    }                                                                        \
    unsigned char* d = Adst0 + ((T) % 3) * BUFB;                             \
    *(uint4*)d = make_uint4(pk[0], pk[1], pk[2], pk[3]);                     \
    *(uint4*)(d + 16) = make_uint4(pk[4], pk[5], pk[6], pk[7]);              \
  }

  // prologue: queue invariant entering loop = [B(1)=1, A(2)=4]
  LOADA(a0, 0);
  DMAB(0);
  LOADA(a1, 1);
  DMAB(1);
  asm volatile("s_waitcnt vmcnt(6)" ::: "memory");  // A(0) done
  WRITEA(a0, 0);
  LOADA(a0, 2);
  asm volatile("s_waitcnt vmcnt(5)" ::: "memory");  // B(0), A(1) done
  WRITEA(a1, 1);

#define STEP(S, WSET, LSET)                                                  \
  {                                                                          \
    const int s_ = (S);                                                      \
    asm volatile("s_waitcnt lgkmcnt(0)" ::: "memory");                       \
    __builtin_amdgcn_s_barrier();                                            \
    __builtin_amdgcn_sched_barrier(0);                                       \
    if (s_ + 2 < 32) DMAB(s_ + 2);                                           \
    if (s_ + 3 < 32) LOADA(LSET, s_ + 3);                                    \
    if (s_ <= 28)                                                            \
      asm volatile("s_waitcnt vmcnt(5)" ::: "memory");                       \
    else if (s_ == 29)                                                       \
      asm volatile("s_waitcnt vmcnt(1)" ::: "memory");                       \
    else                                                                     \
      asm volatile("s_waitcnt vmcnt(0)" ::: "memory");                       \
    if (s_ + 2 < 32) WRITEA(WSET, s_ + 2);                                   \
    unsigned char* Al = smem + (s_ % 3) * BUFB;                              \
    unsigned char* Bl = Al + 8192;                                           \
    bf16x8 af[4], bfr[2];                                                    \
    _Pragma("unroll") for (int mi = 0; mi < 4; ++mi)                         \
        af[mi] = *(const bf16x8*)(Al + (wm * 64 + mi * 16 + l15) * 64 + l4 * 16); \
    _Pragma("unroll") for (int nj = 0; nj < 2; ++nj)                         \
        bfr[nj] = *(const bf16x8*)(Bl + (wn * 32 + nj * 16 + l15) * 64 + l4 * 16); \
    __builtin_amdgcn_s_setprio(1);                                           \
    _Pragma("unroll") for (int mi = 0; mi < 4; ++mi)                         \
        _Pragma("unroll") for (int nj = 0; nj < 2; ++nj)                     \
        acc[mi][nj] = __builtin_amdgcn_mfma_f32_16x16x32_bf16(af[mi], bfr[nj], \
                                                              acc[mi][nj], 0, 0, 0); \
    __builtin_amdgcn_s_setprio(0);                                           \
  }

  for (int s2 = 0; s2 < 32; s2 += 2) {
    STEP(s2, a0, a1);      // even: write tile s+2 (set0), load tile s+3 (set1)
    STEP(s2 + 1, a1, a0);  // odd:  write set1, load set0
  }
#undef STEP
#undef LOADA
#undef DMAB
#undef WRITEA

  const int row0 = mt * 128 + wm * 64;
  const int col0 = nt * 64 + wn * 32;
#pragma unroll
  for (int nj = 0; nj < 2; ++nj) {
    const int col = col0 + nj * 16 + l15;
    const float bv = bvv[nj];
    const int h = col >> 6, d = col & 63;
    if (mode == 3) {
      // V^T: pack 4 consecutive n per (mi,nj)
#pragma unroll
      for (int mi = 0; mi < 4; ++mi) {
        const int row = row0 + mi * 16 + l4 * 4;
        const int b = row >> 11, n = row & (SEQ - 1);
        ushort4 o;
        o.x = f2b(acc[mi][nj][0] + bv);
        o.y = f2b(acc[mi][nj][1] + bv);
        o.z = f2b(acc[mi][nj][2] + bv);
        o.w = f2b(acc[mi][nj][3] + bv);
        *(ushort4*)(outb + ((size_t)(b * NH + h) * HD + d) * SEQ + n) = o;
      }
    } else {
#pragma unroll
      for (int mi = 0; mi < 4; ++mi) {
#pragma unroll
        for (int r = 0; r < 4; ++r) {
          const int row = row0 + mi * 16 + l4 * 4 + r;
          float v = acc[mi][nj][r] + bv;
          if (mode == 0) v *= QSCALE;
          const int b = row >> 11, n = row & (SEQ - 1);
          outb[(((size_t)(b * NH + h) * SEQ + n) << 6) + d] = f2b(v);
        }
      }
    }
  }
}

// ---------------- O-projection: AO bf16 [4096,1024] @ wo^T + bo -> f32 ------
// R5/R7-proven gload_lds path, mode-2 only.
__device__ __forceinline__ void projo_stage(
    const unsigned short* __restrict__ X, const unsigned short* __restrict__ W,
    int mt, int nt, int k0, unsigned char* buf, int wid, int lane) {
#pragma unroll
  for (int is = 0; is < 2; ++is) {
    const int p = (wid * 2 + is) * 1024 + lane * 16;
    gload16(X + (size_t)(mt * 128 + (p >> 6)) * CH + k0 + ((p & 63) >> 1),
            buf + (wid * 2 + is) * 1024);
  }
  {
    const int p = wid * 1024 + lane * 16;
    gload16(W + (size_t)(nt * 64 + (p >> 6)) * CH + k0 + ((p & 63) >> 1),
            buf + 8192 + wid * 1024);
  }
}

__global__ __launch_bounds__(256, 4) void projo_kernel(
    const unsigned short* __restrict__ X, const unsigned short* __restrict__ W,
    const float* __restrict__ bias, float* __restrict__ outf) {
  constexpr int BUFB = 8192 + 4096;
  __shared__ __align__(16) unsigned char smem[3 * BUFB];
  const int tid = threadIdx.x, wid = tid >> 6, lane = tid & 63;
  const int wm = wid >> 1, wn = wid & 1;
  const int mt = blockIdx.x, nt = blockIdx.y;
  const int l15 = lane & 15, l4 = lane >> 4;

  float bvv[2];
#pragma unroll
  for (int nj = 0; nj < 2; ++nj)
    bvv[nj] = bias[nt * 64 + wn * 32 + nj * 16 + l15];

  f32x4 acc[4][2] = {};

  projo_stage(X, W, mt, nt, 0, smem, wid, lane);
  projo_stage(X, W, mt, nt, 32, smem + BUFB, wid, lane);

  for (int s = 0; s < 32; ++s) {
    if (s < 31) asm volatile("s_waitcnt vmcnt(3)" ::: "memory");
    else        asm volatile("s_waitcnt vmcnt(0)" ::: "memory");
    __builtin_amdgcn_s_barrier();
    __builtin_amdgcn_sched_barrier(0);
    if (s + 2 < 32)
      projo_stage(X, W, mt, nt, (s + 2) * 32, smem + ((s + 2) % 3) * BUFB, wid, lane);

    unsigned char* Al = smem + (s % 3) * BUFB;
    unsigned char* Bl = Al + 8192;
    bf16x8 af[4], bfr[2];
#pragma unroll
    for (int mi = 0; mi < 4; ++mi)
      af[mi] = *(const bf16x8*)(Al + (wm * 64 + mi * 16 + l15) * 64 + l4 * 16);
#pragma unroll
    for (int nj = 0; nj < 2; ++nj)
      bfr[nj] = *(const bf16x8*)(Bl + (wn * 32 + nj * 16 + l15) * 64 + l4 * 16);
    __builtin_amdgcn_s_setprio(1);
#pragma unroll
    for (int mi = 0; mi < 4; ++mi)
#pragma unroll
      for (int nj = 0; nj < 2; ++nj)
        acc[mi][nj] = __builtin_amdgcn_mfma_f32_16x16x32_bf16(af[mi], bfr[nj], acc[mi][nj], 0, 0, 0);
    __builtin_amdgcn_s_setprio(0);
  }

  const int row0 = mt * 128 + wm * 64;
  const int col0 = nt * 64 + wn * 32;
#pragma unroll
  for (int nj = 0; nj < 2; ++nj) {
    const int col = col0 + nj * 16 + l15;
    const float bv = bvv[nj];
#pragma unroll
    for (int mi = 0; mi < 4; ++mi)
#pragma unroll
      for (int r = 0; r < 4; ++r)
        outf[(size_t)(row0 + mi * 16 + l4 * 4 + r) * CH + col] = acc[mi][nj][r] + bv;
  }
}

// ---------------- flash attention: in-block split-K, 8 waves (R7 verbatim) --
__device__ __forceinline__ void stage_kv(
    const unsigned short* __restrict__ Kb, const unsigned short* __restrict__ Vb,
    int j0, unsigned char* buf, int ws3, int lane) {
#pragma unroll
  for (int is = 0; is < 2; ++is) {
    const int p = ws3 * 2048 + is * 1024 + lane * 16;
    const int row = p >> 7;
    const int sw = ((p & 127) ^ ((row & 7) << 4)) >> 1;
    gload16(Kb + (size_t)(j0 + row) * HD + sw, buf + ws3 * 2048 + is * 1024);
    gload16(Vb + (size_t)row * SEQ + j0 + sw, buf + 8192 + ws3 * 2048 + is * 1024);
  }
}

__global__ __launch_bounds__(512, 4) void attn_kernel(
    const unsigned short* __restrict__ Qh, const unsigned short* __restrict__ Kh,
    const unsigned short* __restrict__ Vt, unsigned short* __restrict__ AO) {
  __shared__ __align__(16) unsigned char smem[81920];
  const int tid = threadIdx.x, wid = tid >> 6, lane = tid & 63;
  const int l31 = lane & 31, h = lane >> 5;
  const int grp = wid >> 2, wq = wid & 3;
  const int bid = blockIdx.x;
  const int swz = (bid & 7) * 64 + (bid >> 3);  // bijective: 512 % 8 == 0
  const int qt = swz & 15, bh = swz >> 4;

  const unsigned short* Qb = Qh + ((size_t)bh * SEQ + qt * 128) * HD;
  const unsigned short* Kb = Kh + (size_t)bh * SEQ * HD;
  const unsigned short* Vb = Vt + (size_t)bh * HD * SEQ;
  unsigned char* kvb = smem + grp * 32768;
  unsigned char* Qreg = smem + 65536;
  const int jbase = grp * 16;

#pragma unroll
  for (int is = 0; is < 4; ++is) {
    const int p = wq * 4096 + is * 1024 + lane * 16;
    const int row = p >> 7;
    const int sw = ((p & 127) ^ ((row & 7) << 4)) >> 1;
    gload16(Qb + (size_t)row * HD + sw, Qreg + wq * 4096 + is * 1024);
  }
  stage_kv(Kb, Vb, jbase * 64, kvb, wq, lane);
  asm volatile("s_waitcnt vmcnt(4)" ::: "memory");

  bf16x8 qf[4];
  const int qrow = wq * 32 + l31;
#pragma unroll
  for (int ks = 0; ks < 4; ++ks)
    qf[ks] = *(const bf16x8*)(Qreg + qrow * 128 +
                              ((ks * 32 + h * 16) ^ ((qrow & 7) << 4)));

  stage_kv(Kb, Vb, (jbase + 1) * 64, kvb + 16384, wq, lane);

  f32x16 O[2] = {};
  float m = -1e30f, l = 0.f;

  for (int it = 0; it < 16; ++it) {
    if (it < 15) asm volatile("s_waitcnt vmcnt(4)" ::: "memory");
    else         asm volatile("s_waitcnt vmcnt(0)" ::: "memory");
    __builtin_amdgcn_s_barrier();
    __builtin_amdgcn_sched_barrier(0);

    unsigned char* Kc = kvb + ((it & 1) << 14);
    unsigned char* Vc = Kc + 8192;

    f32x16 st[2] = {};
    __builtin_amdgcn_s_setprio(1);
#pragma unroll
    for (int kb = 0; kb < 2; ++kb) {
#pragma unroll
      for (int ks = 0; ks < 4; ++ks) {
        const int krow = kb * 32 + l31;
        const bf16x8 kf = *(const bf16x8*)(Kc + krow * 128 +
                                           ((ks * 32 + h * 16) ^ ((krow & 7) << 4)));
        st[kb] = __builtin_amdgcn_mfma_f32_32x32x16_bf16(kf, qf[ks], st[kb], 0, 0, 0);
      }
    }
    __builtin_amdgcn_s_setprio(0);

    float t[8];
#pragma unroll
    for (int i = 0; i < 8; ++i)
      t[i] = fmaxf(fmaxf(st[0][i], st[0][i + 8]), fmaxf(st[1][i], st[1][i + 8]));
#pragma unroll
    for (int i = 0; i < 4; ++i) t[i] = fmaxf(t[i], t[i + 4]);
    float pmax = fmaxf(fmaxf(t[0], t[1]), fmaxf(t[2], t[3]));
    pmax = fmaxf(pmax, __shfl_xor(pmax, 32));
    if (__any(pmax > m + 8.f)) {
      const float mnew = fmaxf(m, pmax);
      const float alpha = fexp2(m - mnew);
#pragma unroll
      for (int r = 0; r < 16; ++r) {
        const int qO = (r & 3) + 8 * (r >> 2) + 4 * h;
        const float aO = __shfl(alpha, qO);
        O[0][r] *= aO;
        O[1][r] *= aO;
      }
      l *= alpha;
      m = mnew;
    }
#pragma unroll
    for (int kb = 0; kb < 2; ++kb)
#pragma unroll
      for (int i = 0; i < 16; ++i) st[kb][i] = fexp2(st[kb][i] - m);
    float s[8];
#pragma unroll
    for (int i = 0; i < 8; ++i)
      s[i] = (st[0][i] + st[0][i + 8]) + (st[1][i] + st[1][i + 8]);
#pragma unroll
    for (int i = 0; i < 4; ++i) s[i] += s[i + 4];
    float rs = (s[0] + s[1]) + (s[2] + s[3]);
    rs += __shfl_xor(rs, 32);
    l += rs;

    unsigned int pk[2][8];
#pragma unroll
    for (int kb = 0; kb < 2; ++kb)
#pragma unroll
      for (int j = 0; j < 8; ++j)
        pk[kb][j] = cvtpk(st[kb][2 * j], st[kb][2 * j + 1]);

    __builtin_amdgcn_s_setprio(1);
#pragma unroll
    for (int kk = 0; kk < 4; ++kk) {
      const int kb = kk >> 1, j0 = (kk & 1) * 4;
      const unsigned int p0 = pk[kb][j0 + 0], p1 = pk[kb][j0 + 1];
      const unsigned int p2 = pk[kb][j0 + 2], p3 = pk[kb][j0 + 3];
      const unsigned int u0 = h ? p0 : p2;
      const unsigned int u1 = h ? p1 : p3;
      const unsigned int su0 = __shfl_xor(u0, 32);
      const unsigned int su1 = __shfl_xor(u1, 32);
      const unsigned int d0 = h ? su0 : p0;
      const unsigned int d1 = h ? su1 : p1;
      const unsigned int d2 = h ? p2 : su0;
      const unsigned int d3 = h ? p3 : su1;
      uint4 aw = make_uint4(d0, d1, d2, d3);
      const bf16x8 af = *(const bf16x8*)&aw;
#pragma unroll
      for (int db = 0; db < 2; ++db) {
        const int vrow = db * 32 + l31;
        const bf16x8 vf = *(const bf16x8*)(Vc + vrow * 128 +
                                           ((kk * 32 + h * 16) ^ ((vrow & 7) << 4)));
        O[db] = __builtin_amdgcn_mfma_f32_32x32x16_bf16(af, vf, O[db], 0, 0, 0);
      }
    }
    __builtin_amdgcn_s_setprio(0);

    __builtin_amdgcn_s_barrier();
    if (it + 2 < 16)
      stage_kv(Kb, Vb, (jbase + it + 2) * 64, Kc, wq, lane);
  }

  float2* slotO = (float2*)(smem + wq * 8960);
  float2* slotML = (float2*)(smem + wq * 8960 + 8704);
  if (grp == 1) {
    float2* dst = slotO + lane * 17;
#pragma unroll
    for (int i = 0; i < 8; ++i) dst[i] = make_float2(O[0][2 * i], O[0][2 * i + 1]);
#pragma unroll
    for (int i = 0; i < 8; ++i) dst[8 + i] = make_float2(O[1][2 * i], O[1][2 * i + 1]);
    if (h == 0) slotML[l31] = make_float2(m, l);
  }
  __builtin_amdgcn_s_barrier();
  if (grp == 0) {
    const float* src = (const float*)(slotO + lane * 17);
    const float2 ml1 = slotML[l31];
    const float mm = fmaxf(m, ml1.x);
    const float a0 = fexp2(m - mm), a1 = fexp2(ml1.x - mm);
    const float inv = 1.f / (a0 * l + a1 * ml1.y);
    const float w0 = a0 * inv, w1 = a1 * inv;
    const int b = bh >> 4, hh = bh & 15;
#pragma unroll
    for (int r = 0; r < 16; ++r) {
      const int qO = (r & 3) + 8 * (r >> 2) + 4 * h;
      const float s0 = __shfl(w0, qO), s1 = __shfl(w1, qO);
      const int n = qt * 128 + wq * 32 + qO;
      const size_t base = ((size_t)(b * SEQ + n)) * CH + hh * HD;
      AO[base + l31] = f2b(O[0][r] * s0 + src[r] * s1);
      AO[base + 32 + l31] = f2b(O[1][r] * s0 + src[16 + r] * s1);
    }
  }
}

extern "C" void kernel_launch(void* const* d_in, const int* in_sizes, int n_in,
                              void* d_out, int out_size, void* d_ws, size_t ws_size,
                              hipStream_t stream) {
  (void)in_sizes; (void)n_in; (void)out_size; (void)ws_size;
  const float* q  = (const float*)d_in[0];
  const float* k  = (const float*)d_in[1];
  const float* v  = (const float*)d_in[2];
  const float* wq = (const float*)d_in[3];
  const float* bq = (const float*)d_in[4];
  const float* wk = (const float*)d_in[5];
  const float* bk = (const float*)d_in[6];
  const float* wv = (const float*)d_in[7];
  const float* bv = (const float*)d_in[8];
  const float* wo = (const float*)d_in[9];
  const float* bo = (const float*)d_in[10];

  unsigned char* ws = (unsigned char*)d_ws;
  const size_t MB8 = 8u << 20;
  unsigned short* AO  = (unsigned short*)(ws + 0 * MB8);
  unsigned short* Vt  = (unsigned short*)(ws + 1 * MB8);
  unsigned short* wqb = (unsigned short*)(ws + 3 * MB8);
  unsigned short* wkb = (unsigned short*)(ws + 3 * MB8 + 1 * 2097152);
  unsigned short* wvb = (unsigned short*)(ws + 3 * MB8 + 2 * 2097152);
  unsigned short* wob = (unsigned short*)(ws + 3 * MB8 + 3 * 2097152);
  unsigned short* Qh  = (unsigned short*)(ws + 4 * MB8);
  unsigned short* Kh  = (unsigned short*)(ws + 5 * MB8);
  float* out = (float*)d_out;

  CvtArgs ca;
  ca.src[0] = wq; ca.dst[0] = wqb; ca.n4[0] = CH * CH / 4;
  ca.src[1] = wk; ca.dst[1] = wkb; ca.n4[1] = CH * CH / 4;
  ca.src[2] = wv; ca.dst[2] = wvb; ca.n4[2] = CH * CH / 4;
  ca.src[3] = wo; ca.dst[3] = wob; ca.n4[3] = CH * CH / 4;
  cvt_kernel<<<dim3(512, 4), 256, 0, stream>>>(ca);

  Proj3Args p3;
  p3.X[0] = q; p3.W[0] = wqb; p3.bias[0] = bq; p3.outb[0] = Qh; p3.mode[0] = 0;
  p3.X[1] = k; p3.W[1] = wkb; p3.bias[1] = bk; p3.outb[1] = Kh; p3.mode[1] = 1;
  p3.X[2] = v; p3.W[2] = wvb; p3.bias[2] = bv; p3.outb[2] = Vt; p3.mode[2] = 3;
  proj3_kernel<<<dim3(32, 16, 3), 256, 0, stream>>>(p3);

  attn_kernel<<<dim3(512), 512, 0, stream>>>(Qh, Kh, Vt, AO);

  projo_kernel<<<dim3(32, 16), 256, 0, stream>>>(AO, wob, bo, out);
}

// Round 9
// 131.492 us; speedup vs baseline: 1.0996x; 1.0996x over previous
//
#include <hip/hip_runtime.h>

// MHA b=2 n=2048 c=1024 h=16 d=64. bf16 MFMA everywhere, f32 accum.
// R9: proj3 rebuilt on the R7-attn-proven 2-buffer schedule: A staged as RAW
//     f32 via global_load_lds (conversion at fragment read via cvt_pk);
//     swizzled A (^(r&7)<<4) and B (^(r&3)<<4) LDS layouts. attn/projo/cvt
//     unchanged from R7/R8 (proven).
// ws: [0,8M) AO | [8M,16M) Vt | [24M,32M) w*b | [32M,40M) Qh | [40M,48M) Kh.

typedef float f32x4 __attribute__((ext_vector_type(4)));
typedef float f32x16 __attribute__((ext_vector_type(16)));
typedef __bf16 bf16x8 __attribute__((ext_vector_type(8)));

#define SEQ 2048
#define CH 1024
#define NH 16
#define HD 64
#define TOK 4096
// 0.125 (d^-1/2) * log2(e): fold softmax base-2 conversion into Q
#define QSCALE 0.18033688011112042f

__device__ __forceinline__ unsigned short f2b(float f) {
  unsigned int u = __float_as_uint(f);
  u = (u + 0x7FFFu + ((u >> 16) & 1u)) >> 16;  // RNE
  return (unsigned short)u;
}

__device__ __forceinline__ float fexp2(float x) {  // guaranteed single v_exp_f32
  float r;
  asm("v_exp_f32 %0, %1" : "=v"(r) : "v"(x));
  return r;
}

__device__ __forceinline__ unsigned int cvtpk(float lo, float hi) {
  unsigned int r;
  asm("v_cvt_pk_bf16_f32 %0, %1, %2" : "=v"(r) : "v"(lo), "v"(hi));
  return r;
}

__device__ __forceinline__ void gload16(const void* g, void* l) {
  __builtin_amdgcn_global_load_lds(
      (const __attribute__((address_space(1))) unsigned int*)g,
      (__attribute__((address_space(3))) unsigned int*)l, 16, 0, 0);
}

// ---------------- f32 -> bf16 conversion (weights only) ----------------
struct CvtArgs {
  const float* src[4];
  unsigned short* dst[4];
  int n4[4];
};

__global__ __launch_bounds__(256) void cvt_kernel(CvtArgs a) {
  const int s = blockIdx.y;
  const int n4 = a.n4[s];
  const float4* __restrict__ src = (const float4*)a.src[s];
  unsigned short* __restrict__ dst = a.dst[s];
  const int stride = gridDim.x * blockDim.x;
  for (int i = blockIdx.x * blockDim.x + threadIdx.x; i < n4; i += stride) {
    float4 w = src[i];
    ushort4 o;
    o.x = f2b(w.x); o.y = f2b(w.y); o.z = f2b(w.z); o.w = f2b(w.w);
    *(ushort4*)(dst + 4 * (size_t)i) = o;
  }
}

// ---------------- fused-cvt GEMM: Xf32[4096,1024] @ W^T + bias --------------
// 128x64 tile, BK=32. A staged RAW f32 (16KB) via gload_lds w/ swizzled src;
// B bf16 (4KB) likewise. 2 buffers, R7-attn race-free counted-vmcnt schedule.
// mode 0: bf16 head layout [bh][n][d] scaled by QSCALE (Q)
// mode 1: bf16 head layout (K)
// mode 3: bf16 transposed head layout [bh][d][n] (V^T)
struct Proj3Args {
  const float* X[3];
  const unsigned short* W[3];
  const float* bias[3];
  unsigned short* outb[3];
  int mode[3];
};

__device__ __forceinline__ void p3_stage(
    const float* __restrict__ X, const unsigned short* __restrict__ W,
    int mt, int nt, int k0, unsigned char* buf, int wid, int lane) {
  // A: 128 rows x 128B (f32), linear dest; source pre-swizzled ^(row&7)<<4
#pragma unroll
  for (int is = 0; is < 4; ++is) {
    const int p = wid * 4096 + is * 1024 + lane * 16;
    const int row = p >> 7;
    const int so = ((p & 127) ^ ((row & 7) << 4)) >> 2;  // float offset in row
    gload16(X + (size_t)(mt * 128 + row) * CH + k0 + so, buf + p);
  }
  // B: 64 rows x 64B (bf16); source pre-swizzled ^(row&3)<<4
  {
    const int p = wid * 1024 + lane * 16;
    const int row = p >> 6;
    const int so = ((p & 63) ^ ((row & 3) << 4)) >> 1;  // bf16 offset in row
    gload16(W + (size_t)(nt * 64 + row) * CH + k0 + so, buf + 16384 + p);
  }
}

__global__ __launch_bounds__(256, 4) void proj3_kernel(Proj3Args a) {
  constexpr int ABYTES = 16384;        // 128 x 32 f32
  constexpr int BUFB = ABYTES + 4096;  // + 64 x 32 bf16
  __shared__ __align__(16) unsigned char smem[2 * BUFB];
  const int z = blockIdx.z;
  const float* __restrict__ X = a.X[z];
  const unsigned short* __restrict__ W = a.W[z];
  const float* __restrict__ bias = a.bias[z];
  unsigned short* __restrict__ outb = a.outb[z];
  const int mode = a.mode[z];
  const int tid = threadIdx.x, wid = tid >> 6, lane = tid & 63;
  const int wm = wid >> 1, wn = wid & 1;
  const int mt = blockIdx.x, nt = blockIdx.y;
  const int l15 = lane & 15, l4 = lane >> 4;

  // bias loads issued before stage(0): oldest in queue, drained by first wait
  float bvv[2];
#pragma unroll
  for (int nj = 0; nj < 2; ++nj)
    bvv[nj] = bias[nt * 64 + wn * 32 + nj * 16 + l15];

  f32x4 acc[4][2] = {};

  p3_stage(X, W, mt, nt, 0, smem, wid, lane);
  p3_stage(X, W, mt, nt, 32, smem + BUFB, wid, lane);

  for (int s = 0; s < 32; ++s) {
    // complete OWN tile-s loads; barrier => ALL waves' tile-s loads complete
    if (s < 31) asm volatile("s_waitcnt vmcnt(5)" ::: "memory");
    else        asm volatile("s_waitcnt vmcnt(0)" ::: "memory");
    __builtin_amdgcn_s_barrier();
    __builtin_amdgcn_sched_barrier(0);

    unsigned char* Al = smem + (s & 1) * BUFB;
    unsigned char* Bl = Al + ABYTES;

    bf16x8 af[4], bfr[2];
#pragma unroll
    for (int mi = 0; mi < 4; ++mi) {
      const int r = wm * 64 + mi * 16 + l15;
      const int swz = (r & 7) << 4;
      const f32x4 lo = *(const f32x4*)(Al + r * 128 + ((l4 * 32) ^ swz));
      const f32x4 hi = *(const f32x4*)(Al + r * 128 + ((l4 * 32 + 16) ^ swz));
      const uint4 aw = make_uint4(cvtpk(lo[0], lo[1]), cvtpk(lo[2], lo[3]),
                                  cvtpk(hi[0], hi[1]), cvtpk(hi[2], hi[3]));
      af[mi] = *(const bf16x8*)&aw;
    }
#pragma unroll
    for (int nj = 0; nj < 2; ++nj) {
      const int rb = wn * 32 + nj * 16 + l15;
      bfr[nj] = *(const bf16x8*)(Bl + rb * 64 + ((l4 * 16) ^ ((rb & 3) << 4)));
    }
    __builtin_amdgcn_s_setprio(1);
#pragma unroll
    for (int mi = 0; mi < 4; ++mi)
#pragma unroll
      for (int nj = 0; nj < 2; ++nj)
        acc[mi][nj] = __builtin_amdgcn_mfma_f32_16x16x32_bf16(af[mi], bfr[nj], acc[mi][nj], 0, 0, 0);
    __builtin_amdgcn_s_setprio(0);

    // all waves done reading buf[s&1]; refill it with tile s+2
    __builtin_amdgcn_s_barrier();
    if (s + 2 < 32)
      p3_stage(X, W, mt, nt, (s + 2) * 32, Al, wid, lane);
  }

  const int row0 = mt * 128 + wm * 64;
  const int col0 = nt * 64 + wn * 32;
#pragma unroll
  for (int nj = 0; nj < 2; ++nj) {
    const int col = col0 + nj * 16 + l15;
    const float bv = bvv[nj];
    const int h = col >> 6, d = col & 63;
    if (mode == 3) {
      // V^T: pack 4 consecutive n per (mi,nj)
#pragma unroll
      for (int mi = 0; mi < 4; ++mi) {
        const int row = row0 + mi * 16 + l4 * 4;
        const int b = row >> 11, n = row & (SEQ - 1);
        ushort4 o;
        o.x = f2b(acc[mi][nj][0] + bv);
        o.y = f2b(acc[mi][nj][1] + bv);
        o.z = f2b(acc[mi][nj][2] + bv);
        o.w = f2b(acc[mi][nj][3] + bv);
        *(ushort4*)(outb + ((size_t)(b * NH + h) * HD + d) * SEQ + n) = o;
      }
    } else {
#pragma unroll
      for (int mi = 0; mi < 4; ++mi) {
#pragma unroll
        for (int r = 0; r < 4; ++r) {
          const int row = row0 + mi * 16 + l4 * 4 + r;
          float v = acc[mi][nj][r] + bv;
          if (mode == 0) v *= QSCALE;
          const int b = row >> 11, n = row & (SEQ - 1);
          outb[(((size_t)(b * NH + h) * SEQ + n) << 6) + d] = f2b(v);
        }
      }
    }
  }
}

// ---------------- O-projection: AO bf16 [4096,1024] @ wo^T + bo -> f32 ------
__device__ __forceinline__ void projo_stage(
    const unsigned short* __restrict__ X, const unsigned short* __restrict__ W,
    int mt, int nt, int k0, unsigned char* buf, int wid, int lane) {
#pragma unroll
  for (int is = 0; is < 2; ++is) {
    const int p = (wid * 2 + is) * 1024 + lane * 16;
    gload16(X + (size_t)(mt * 128 + (p >> 6)) * CH + k0 + ((p & 63) >> 1),
            buf + (wid * 2 + is) * 1024);
  }
  {
    const int p = wid * 1024 + lane * 16;
    gload16(W + (size_t)(nt * 64 + (p >> 6)) * CH + k0 + ((p & 63) >> 1),
            buf + 8192 + wid * 1024);
  }
}

__global__ __launch_bounds__(256, 4) void projo_kernel(
    const unsigned short* __restrict__ X, const unsigned short* __restrict__ W,
    const float* __restrict__ bias, float* __restrict__ outf) {
  constexpr int BUFB = 8192 + 4096;
  __shared__ __align__(16) unsigned char smem[3 * BUFB];
  const int tid = threadIdx.x, wid = tid >> 6, lane = tid & 63;
  const int wm = wid >> 1, wn = wid & 1;
  const int mt = blockIdx.x, nt = blockIdx.y;
  const int l15 = lane & 15, l4 = lane >> 4;

  float bvv[2];
#pragma unroll
  for (int nj = 0; nj < 2; ++nj)
    bvv[nj] = bias[nt * 64 + wn * 32 + nj * 16 + l15];

  f32x4 acc[4][2] = {};

  projo_stage(X, W, mt, nt, 0, smem, wid, lane);
  projo_stage(X, W, mt, nt, 32, smem + BUFB, wid, lane);

  for (int s = 0; s < 32; ++s) {
    if (s < 31) asm volatile("s_waitcnt vmcnt(3)" ::: "memory");
    else        asm volatile("s_waitcnt vmcnt(0)" ::: "memory");
    __builtin_amdgcn_s_barrier();
    __builtin_amdgcn_sched_barrier(0);
    if (s + 2 < 32)
      projo_stage(X, W, mt, nt, (s + 2) * 32, smem + ((s + 2) % 3) * BUFB, wid, lane);

    unsigned char* Al = smem + (s % 3) * BUFB;
    unsigned char* Bl = Al + 8192;
    bf16x8 af[4], bfr[2];
#pragma unroll
    for (int mi = 0; mi < 4; ++mi)
      af[mi] = *(const bf16x8*)(Al + (wm * 64 + mi * 16 + l15) * 64 + l4 * 16);
#pragma unroll
    for (int nj = 0; nj < 2; ++nj)
      bfr[nj] = *(const bf16x8*)(Bl + (wn * 32 + nj * 16 + l15) * 64 + l4 * 16);
    __builtin_amdgcn_s_setprio(1);
#pragma unroll
    for (int mi = 0; mi < 4; ++mi)
#pragma unroll
      for (int nj = 0; nj < 2; ++nj)
        acc[mi][nj] = __builtin_amdgcn_mfma_f32_16x16x32_bf16(af[mi], bfr[nj], acc[mi][nj], 0, 0, 0);
    __builtin_amdgcn_s_setprio(0);
  }

  const int row0 = mt * 128 + wm * 64;
  const int col0 = nt * 64 + wn * 32;
#pragma unroll
  for (int nj = 0; nj < 2; ++nj) {
    const int col = col0 + nj * 16 + l15;
    const float bv = bvv[nj];
#pragma unroll
    for (int mi = 0; mi < 4; ++mi)
#pragma unroll
      for (int r = 0; r < 4; ++r)
        outf[(size_t)(row0 + mi * 16 + l4 * 4 + r) * CH + col] = acc[mi][nj][r] + bv;
  }
}

// ---------------- flash attention: in-block split-K, 8 waves (R7 verbatim) --
__device__ __forceinline__ void stage_kv(
    const unsigned short* __restrict__ Kb, const unsigned short* __restrict__ Vb,
    int j0, unsigned char* buf, int ws3, int lane) {
#pragma unroll
  for (int is = 0; is < 2; ++is) {
    const int p = ws3 * 2048 + is * 1024 + lane * 16;
    const int row = p >> 7;
    const int sw = ((p & 127) ^ ((row & 7) << 4)) >> 1;
    gload16(Kb + (size_t)(j0 + row) * HD + sw, buf + ws3 * 2048 + is * 1024);
    gload16(Vb + (size_t)row * SEQ + j0 + sw, buf + 8192 + ws3 * 2048 + is * 1024);
  }
}

__global__ __launch_bounds__(512, 4) void attn_kernel(
    const unsigned short* __restrict__ Qh, const unsigned short* __restrict__ Kh,
    const unsigned short* __restrict__ Vt, unsigned short* __restrict__ AO) {
  __shared__ __align__(16) unsigned char smem[81920];
  const int tid = threadIdx.x, wid = tid >> 6, lane = tid & 63;
  const int l31 = lane & 31, h = lane >> 5;
  const int grp = wid >> 2, wq = wid & 3;
  const int bid = blockIdx.x;
  const int swz = (bid & 7) * 64 + (bid >> 3);  // bijective: 512 % 8 == 0
  const int qt = swz & 15, bh = swz >> 4;

  const unsigned short* Qb = Qh + ((size_t)bh * SEQ + qt * 128) * HD;
  const unsigned short* Kb = Kh + (size_t)bh * SEQ * HD;
  const unsigned short* Vb = Vt + (size_t)bh * HD * SEQ;
  unsigned char* kvb = smem + grp * 32768;
  unsigned char* Qreg = smem + 65536;
  const int jbase = grp * 16;

#pragma unroll
  for (int is = 0; is < 4; ++is) {
    const int p = wq * 4096 + is * 1024 + lane * 16;
    const int row = p >> 7;
    const int sw = ((p & 127) ^ ((row & 7) << 4)) >> 1;
    gload16(Qb + (size_t)row * HD + sw, Qreg + wq * 4096 + is * 1024);
  }
  stage_kv(Kb, Vb, jbase * 64, kvb, wq, lane);
  asm volatile("s_waitcnt vmcnt(4)" ::: "memory");

  bf16x8 qf[4];
  const int qrow = wq * 32 + l31;
#pragma unroll
  for (int ks = 0; ks < 4; ++ks)
    qf[ks] = *(const bf16x8*)(Qreg + qrow * 128 +
                              ((ks * 32 + h * 16) ^ ((qrow & 7) << 4)));

  stage_kv(Kb, Vb, (jbase + 1) * 64, kvb + 16384, wq, lane);

  f32x16 O[2] = {};
  float m = -1e30f, l = 0.f;

  for (int it = 0; it < 16; ++it) {
    if (it < 15) asm volatile("s_waitcnt vmcnt(4)" ::: "memory");
    else         asm volatile("s_waitcnt vmcnt(0)" ::: "memory");
    __builtin_amdgcn_s_barrier();
    __builtin_amdgcn_sched_barrier(0);

    unsigned char* Kc = kvb + ((it & 1) << 14);
    unsigned char* Vc = Kc + 8192;

    f32x16 st[2] = {};
    __builtin_amdgcn_s_setprio(1);
#pragma unroll
    for (int kb = 0; kb < 2; ++kb) {
#pragma unroll
      for (int ks = 0; ks < 4; ++ks) {
        const int krow = kb * 32 + l31;
        const bf16x8 kf = *(const bf16x8*)(Kc + krow * 128 +
                                           ((ks * 32 + h * 16) ^ ((krow & 7) << 4)));
        st[kb] = __builtin_amdgcn_mfma_f32_32x32x16_bf16(kf, qf[ks], st[kb], 0, 0, 0);
      }
    }
    __builtin_amdgcn_s_setprio(0);

    float t[8];
#pragma unroll
    for (int i = 0; i < 8; ++i)
      t[i] = fmaxf(fmaxf(st[0][i], st[0][i + 8]), fmaxf(st[1][i], st[1][i + 8]));
#pragma unroll
    for (int i = 0; i < 4; ++i) t[i] = fmaxf(t[i], t[i + 4]);
    float pmax = fmaxf(fmaxf(t[0], t[1]), fmaxf(t[2], t[3]));
    pmax = fmaxf(pmax, __shfl_xor(pmax, 32));
    if (__any(pmax > m + 8.f)) {
      const float mnew = fmaxf(m, pmax);
      const float alpha = fexp2(m - mnew);
#pragma unroll
      for (int r = 0; r < 16; ++r) {
        const int qO = (r & 3) + 8 * (r >> 2) + 4 * h;
        const float aO = __shfl(alpha, qO);
        O[0][r] *= aO;
        O[1][r] *= aO;
      }
      l *= alpha;
      m = mnew;
    }
#pragma unroll
    for (int kb = 0; kb < 2; ++kb)
#pragma unroll
      for (int i = 0; i < 16; ++i) st[kb][i] = fexp2(st[kb][i] - m);
    float s[8];
#pragma unroll
    for (int i = 0; i < 8; ++i)
      s[i] = (st[0][i] + st[0][i + 8]) + (st[1][i] + st[1][i + 8]);
#pragma unroll
    for (int i = 0; i < 4; ++i) s[i] += s[i + 4];
    float rs = (s[0] + s[1]) + (s[2] + s[3]);
    rs += __shfl_xor(rs, 32);
    l += rs;

    unsigned int pk[2][8];
#pragma unroll
    for (int kb = 0; kb < 2; ++kb)
#pragma unroll
      for (int j = 0; j < 8; ++j)
        pk[kb][j] = cvtpk(st[kb][2 * j], st[kb][2 * j + 1]);

    __builtin_amdgcn_s_setprio(1);
#pragma unroll
    for (int kk = 0; kk < 4; ++kk) {
      const int kb = kk >> 1, j0 = (kk & 1) * 4;
      const unsigned int p0 = pk[kb][j0 + 0], p1 = pk[kb][j0 + 1];
      const unsigned int p2 = pk[kb][j0 + 2], p3 = pk[kb][j0 + 3];
      const unsigned int u0 = h ? p0 : p2;
      const unsigned int u1 = h ? p1 : p3;
      const unsigned int su0 = __shfl_xor(u0, 32);
      const unsigned int su1 = __shfl_xor(u1, 32);
      const unsigned int d0 = h ? su0 : p0;
      const unsigned int d1 = h ? su1 : p1;
      const unsigned int d2 = h ? p2 : su0;
      const unsigned int d3 = h ? p3 : su1;
      uint4 aw = make_uint4(d0, d1, d2, d3);
      const bf16x8 af = *(const bf16x8*)&aw;
#pragma unroll
      for (int db = 0; db < 2; ++db) {
        const int vrow = db * 32 + l31;
        const bf16x8 vf = *(const bf16x8*)(Vc + vrow * 128 +
                                           ((kk * 32 + h * 16) ^ ((vrow & 7) << 4)));
        O[db] = __builtin_amdgcn_mfma_f32_32x32x16_bf16(af, vf, O[db], 0, 0, 0);
      }
    }
    __builtin_amdgcn_s_setprio(0);

    __builtin_amdgcn_s_barrier();
    if (it + 2 < 16)
      stage_kv(Kb, Vb, (jbase + it + 2) * 64, Kc, wq, lane);
  }

  float2* slotO = (float2*)(smem + wq * 8960);
  float2* slotML = (float2*)(smem + wq * 8960 + 8704);
  if (grp == 1) {
    float2* dst = slotO + lane * 17;
#pragma unroll
    for (int i = 0; i < 8; ++i) dst[i] = make_float2(O[0][2 * i], O[0][2 * i + 1]);
#pragma unroll
    for (int i = 0; i < 8; ++i) dst[8 + i] = make_float2(O[1][2 * i], O[1][2 * i + 1]);
    if (h == 0) slotML[l31] = make_float2(m, l);
  }
  __builtin_amdgcn_s_barrier();
  if (grp == 0) {
    const float* src = (const float*)(slotO + lane * 17);
    const float2 ml1 = slotML[l31];
    const float mm = fmaxf(m, ml1.x);
    const float a0 = fexp2(m - mm), a1 = fexp2(ml1.x - mm);
    const float inv = 1.f / (a0 * l + a1 * ml1.y);
    const float w0 = a0 * inv, w1 = a1 * inv;
    const int b = bh >> 4, hh = bh & 15;
#pragma unroll
    for (int r = 0; r < 16; ++r) {
      const int qO = (r & 3) + 8 * (r >> 2) + 4 * h;
      const float s0 = __shfl(w0, qO), s1 = __shfl(w1, qO);
      const int n = qt * 128 + wq * 32 + qO;
      const size_t base = ((size_t)(b * SEQ + n)) * CH + hh * HD;
      AO[base + l31] = f2b(O[0][r] * s0 + src[r] * s1);
      AO[base + 32 + l31] = f2b(O[1][r] * s0 + src[16 + r] * s1);
    }
  }
}

extern "C" void kernel_launch(void* const* d_in, const int* in_sizes, int n_in,
                              void* d_out, int out_size, void* d_ws, size_t ws_size,
                              hipStream_t stream) {
  (void)in_sizes; (void)n_in; (void)out_size; (void)ws_size;
  const float* q  = (const float*)d_in[0];
  const float* k  = (const float*)d_in[1];
  const float* v  = (const float*)d_in[2];
  const float* wq = (const float*)d_in[3];
  const float* bq = (const float*)d_in[4];
  const float* wk = (const float*)d_in[5];
  const float* bk = (const float*)d_in[6];
  const float* wv = (const float*)d_in[7];
  const float* bv = (const float*)d_in[8];
  const float* wo = (const float*)d_in[9];
  const float* bo = (const float*)d_in[10];

  unsigned char* ws = (unsigned char*)d_ws;
  const size_t MB8 = 8u << 20;
  unsigned short* AO  = (unsigned short*)(ws + 0 * MB8);
  unsigned short* Vt  = (unsigned short*)(ws + 1 * MB8);
  unsigned short* wqb = (unsigned short*)(ws + 3 * MB8);
  unsigned short* wkb = (unsigned short*)(ws + 3 * MB8 + 1 * 2097152);
  unsigned short* wvb = (unsigned short*)(ws + 3 * MB8 + 2 * 2097152);
  unsigned short* wob = (unsigned short*)(ws + 3 * MB8 + 3 * 2097152);
  unsigned short* Qh  = (unsigned short*)(ws + 4 * MB8);
  unsigned short* Kh  = (unsigned short*)(ws + 5 * MB8);
  float* out = (float*)d_out;

  CvtArgs ca;
  ca.src[0] = wq; ca.dst[0] = wqb; ca.n4[0] = CH * CH / 4;
  ca.src[1] = wk; ca.dst[1] = wkb; ca.n4[1] = CH * CH / 4;
  ca.src[2] = wv; ca.dst[2] = wvb; ca.n4[2] = CH * CH / 4;
  ca.src[3] = wo; ca.dst[3] = wob; ca.n4[3] = CH * CH / 4;
  cvt_kernel<<<dim3(512, 4), 256, 0, stream>>>(ca);

  Proj3Args p3;
  p3.X[0] = q; p3.W[0] = wqb; p3.bias[0] = bq; p3.outb[0] = Qh; p3.mode[0] = 0;
  p3.X[1] = k; p3.W[1] = wkb; p3.bias[1] = bk; p3.outb[1] = Kh; p3.mode[1] = 1;
  p3.X[2] = v; p3.W[2] = wvb; p3.bias[2] = bv; p3.outb[2] = Vt; p3.mode[2] = 3;
  proj3_kernel<<<dim3(32, 16, 3), 256, 0, stream>>>(p3);

  attn_kernel<<<dim3(512), 512, 0, stream>>>(Qh, Kh, Vt, AO);

  projo_kernel<<<dim3(32, 16), 256, 0, stream>>>(AO, wob, bo, out);
}

// Round 10
// 120.262 us; speedup vs baseline: 1.2023x; 1.0934x over previous
//
#include <hip/hip_runtime.h>

// MHA b=2 n=2048 c=1024 h=16 d=64. bf16 MFMA everywhere, f32 accum.
// R10: proj3 128x128 tile (16 MFMA/step/wave, 2x density), grid 768 = exactly
//      one scheduling round at 3 blocks/CU (zero tail). Same race-free
//      2-buffer counted-vmcnt schedule as R7/R9. attn/projo/cvt unchanged.
// ws: [0,8M) AO | [8M,16M) Vt | [24M,32M) w*b | [32M,40M) Qh | [40M,48M) Kh.

typedef float f32x4 __attribute__((ext_vector_type(4)));
typedef float f32x16 __attribute__((ext_vector_type(16)));
typedef __bf16 bf16x8 __attribute__((ext_vector_type(8)));

#define SEQ 2048
#define CH 1024
#define NH 16
#define HD 64
#define TOK 4096
// 0.125 (d^-1/2) * log2(e): fold softmax base-2 conversion into Q
#define QSCALE 0.18033688011112042f

__device__ __forceinline__ unsigned short f2b(float f) {
  unsigned int u = __float_as_uint(f);
  u = (u + 0x7FFFu + ((u >> 16) & 1u)) >> 16;  // RNE
  return (unsigned short)u;
}

__device__ __forceinline__ float fexp2(float x) {  // guaranteed single v_exp_f32
  float r;
  asm("v_exp_f32 %0, %1" : "=v"(r) : "v"(x));
  return r;
}

__device__ __forceinline__ unsigned int cvtpk(float lo, float hi) {
  unsigned int r;
  asm("v_cvt_pk_bf16_f32 %0, %1, %2" : "=v"(r) : "v"(lo), "v"(hi));
  return r;
}

__device__ __forceinline__ void gload16(const void* g, void* l) {
  __builtin_amdgcn_global_load_lds(
      (const __attribute__((address_space(1))) unsigned int*)g,
      (__attribute__((address_space(3))) unsigned int*)l, 16, 0, 0);
}

// ---------------- f32 -> bf16 conversion (weights only) ----------------
struct CvtArgs {
  const float* src[4];
  unsigned short* dst[4];
  int n4[4];
};

__global__ __launch_bounds__(256) void cvt_kernel(CvtArgs a) {
  const int s = blockIdx.y;
  const int n4 = a.n4[s];
  const float4* __restrict__ src = (const float4*)a.src[s];
  unsigned short* __restrict__ dst = a.dst[s];
  const int stride = gridDim.x * blockDim.x;
  for (int i = blockIdx.x * blockDim.x + threadIdx.x; i < n4; i += stride) {
    float4 w = src[i];
    ushort4 o;
    o.x = f2b(w.x); o.y = f2b(w.y); o.z = f2b(w.z); o.w = f2b(w.w);
    *(ushort4*)(dst + 4 * (size_t)i) = o;
  }
}

// ---------------- fused-cvt GEMM: Xf32[4096,1024] @ W^T + bias --------------
// 128x128 tile, BK=32. A staged RAW f32 (16KB, swizzled src ^(r&7)<<4);
// B bf16 (8KB, swizzled src ^(r&3)<<4). 2 buffers (48KB), race-free
// counted-vmcnt(6) schedule. 16 MFMA/step/wave. Grid 768 = 1 round @ 3/CU.
// mode 0: bf16 head layout [bh][n][d] scaled by QSCALE (Q)
// mode 1: bf16 head layout (K)
// mode 3: bf16 transposed head layout [bh][d][n] (V^T)
struct Proj3Args {
  const float* X[3];
  const unsigned short* W[3];
  const float* bias[3];
  unsigned short* outb[3];
  int mode[3];
};

#define P3_ABYTES 16384
#define P3_BUFB (P3_ABYTES + 8192)

__device__ __forceinline__ void p3_stage(
    const float* __restrict__ X, const unsigned short* __restrict__ W,
    int mt, int nt, int k0, unsigned char* buf, int wid, int lane) {
  // A: 128 rows x 128B (f32); linear dest, source pre-swizzled ^(row&7)<<4
#pragma unroll
  for (int is = 0; is < 4; ++is) {
    const int p = wid * 4096 + is * 1024 + lane * 16;
    const int row = p >> 7;
    const int so = ((p & 127) ^ ((row & 7) << 4)) >> 2;  // float offset in row
    gload16(X + (size_t)(mt * 128 + row) * CH + k0 + so, buf + p);
  }
  // B: 128 rows x 64B (bf16); source pre-swizzled ^(row&3)<<4
#pragma unroll
  for (int is = 0; is < 2; ++is) {
    const int p = wid * 2048 + is * 1024 + lane * 16;
    const int row = p >> 6;
    const int so = ((p & 63) ^ ((row & 3) << 4)) >> 1;  // bf16 offset in row
    gload16(W + (size_t)(nt * 128 + row) * CH + k0 + so, buf + P3_ABYTES + p);
  }
}

__global__ __launch_bounds__(256, 3) void proj3_kernel(Proj3Args a) {
  __shared__ __align__(16) unsigned char smem[2 * P3_BUFB];  // 49152
  const int z = blockIdx.z;
  const float* __restrict__ X = a.X[z];
  const unsigned short* __restrict__ W = a.W[z];
  const float* __restrict__ bias = a.bias[z];
  unsigned short* __restrict__ outb = a.outb[z];
  const int mode = a.mode[z];
  const int tid = threadIdx.x, wid = tid >> 6, lane = tid & 63;
  const int wm = wid >> 1, wn = wid & 1;
  const int mt = blockIdx.x, nt = blockIdx.y;
  const int l15 = lane & 15, l4 = lane >> 4;

  // bias loads issued before stage(0): oldest in queue, drained by first wait
  float bvv[4];
#pragma unroll
  for (int nj = 0; nj < 4; ++nj)
    bvv[nj] = bias[nt * 128 + wn * 64 + nj * 16 + l15];

  f32x4 acc[4][4] = {};

  p3_stage(X, W, mt, nt, 0, smem, wid, lane);
  p3_stage(X, W, mt, nt, 32, smem + P3_BUFB, wid, lane);

  for (int s = 0; s < 32; ++s) {
    // complete OWN tile-s loads; barrier => ALL waves' tile-s loads complete
    if (s < 31) asm volatile("s_waitcnt vmcnt(6)" ::: "memory");
    else        asm volatile("s_waitcnt vmcnt(0)" ::: "memory");
    __builtin_amdgcn_s_barrier();
    __builtin_amdgcn_sched_barrier(0);

    unsigned char* Al = smem + (s & 1) * P3_BUFB;
    unsigned char* Bl = Al + P3_ABYTES;

    bf16x8 af[4], bfr[4];
#pragma unroll
    for (int mi = 0; mi < 4; ++mi) {
      const int r = wm * 64 + mi * 16 + l15;
      const int swz = (r & 7) << 4;
      const f32x4 lo = *(const f32x4*)(Al + r * 128 + ((l4 * 32) ^ swz));
      const f32x4 hi = *(const f32x4*)(Al + r * 128 + ((l4 * 32 + 16) ^ swz));
      const uint4 aw = make_uint4(cvtpk(lo[0], lo[1]), cvtpk(lo[2], lo[3]),
                                  cvtpk(hi[0], hi[1]), cvtpk(hi[2], hi[3]));
      af[mi] = *(const bf16x8*)&aw;
    }
#pragma unroll
    for (int nj = 0; nj < 4; ++nj) {
      const int rb = wn * 64 + nj * 16 + l15;
      bfr[nj] = *(const bf16x8*)(Bl + rb * 64 + ((l4 * 16) ^ ((rb & 3) << 4)));
    }
    __builtin_amdgcn_s_setprio(1);
#pragma unroll
    for (int mi = 0; mi < 4; ++mi)
#pragma unroll
      for (int nj = 0; nj < 4; ++nj)
        acc[mi][nj] = __builtin_amdgcn_mfma_f32_16x16x32_bf16(af[mi], bfr[nj], acc[mi][nj], 0, 0, 0);
    __builtin_amdgcn_s_setprio(0);

    // all waves done reading buf[s&1]; refill it with tile s+2
    __builtin_amdgcn_s_barrier();
    if (s + 2 < 32)
      p3_stage(X, W, mt, nt, (s + 2) * 32, Al, wid, lane);
  }

  const int row0 = mt * 128 + wm * 64;
  const int col0 = nt * 128 + wn * 64;
#pragma unroll
  for (int nj = 0; nj < 4; ++nj) {
    const int col = col0 + nj * 16 + l15;
    const float bv = bvv[nj];
    const int h = col >> 6, d = col & 63;
    if (mode == 3) {
      // V^T: pack 4 consecutive n per (mi,nj)
#pragma unroll
      for (int mi = 0; mi < 4; ++mi) {
        const int row = row0 + mi * 16 + l4 * 4;
        const int b = row >> 11, n = row & (SEQ - 1);
        ushort4 o;
        o.x = f2b(acc[mi][nj][0] + bv);
        o.y = f2b(acc[mi][nj][1] + bv);
        o.z = f2b(acc[mi][nj][2] + bv);
        o.w = f2b(acc[mi][nj][3] + bv);
        *(ushort4*)(outb + ((size_t)(b * NH + h) * HD + d) * SEQ + n) = o;
      }
    } else {
#pragma unroll
      for (int mi = 0; mi < 4; ++mi) {
#pragma unroll
        for (int r = 0; r < 4; ++r) {
          const int row = row0 + mi * 16 + l4 * 4 + r;
          float v = acc[mi][nj][r] + bv;
          if (mode == 0) v *= QSCALE;
          const int b = row >> 11, n = row & (SEQ - 1);
          outb[(((size_t)(b * NH + h) * SEQ + n) << 6) + d] = f2b(v);
        }
      }
    }
  }
}

// ---------------- O-projection: AO bf16 [4096,1024] @ wo^T + bo -> f32 ------
__device__ __forceinline__ void projo_stage(
    const unsigned short* __restrict__ X, const unsigned short* __restrict__ W,
    int mt, int nt, int k0, unsigned char* buf, int wid, int lane) {
#pragma unroll
  for (int is = 0; is < 2; ++is) {
    const int p = (wid * 2 + is) * 1024 + lane * 16;
    gload16(X + (size_t)(mt * 128 + (p >> 6)) * CH + k0 + ((p & 63) >> 1),
            buf + (wid * 2 + is) * 1024);
  }
  {
    const int p = wid * 1024 + lane * 16;
    gload16(W + (size_t)(nt * 64 + (p >> 6)) * CH + k0 + ((p & 63) >> 1),
            buf + 8192 + wid * 1024);
  }
}

__global__ __launch_bounds__(256, 4) void projo_kernel(
    const unsigned short* __restrict__ X, const unsigned short* __restrict__ W,
    const float* __restrict__ bias, float* __restrict__ outf) {
  constexpr int BUFB = 8192 + 4096;
  __shared__ __align__(16) unsigned char smem[3 * BUFB];
  const int tid = threadIdx.x, wid = tid >> 6, lane = tid & 63;
  const int wm = wid >> 1, wn = wid & 1;
  const int mt = blockIdx.x, nt = blockIdx.y;
  const int l15 = lane & 15, l4 = lane >> 4;

  float bvv[2];
#pragma unroll
  for (int nj = 0; nj < 2; ++nj)
    bvv[nj] = bias[nt * 64 + wn * 32 + nj * 16 + l15];

  f32x4 acc[4][2] = {};

  projo_stage(X, W, mt, nt, 0, smem, wid, lane);
  projo_stage(X, W, mt, nt, 32, smem + BUFB, wid, lane);

  for (int s = 0; s < 32; ++s) {
    if (s < 31) asm volatile("s_waitcnt vmcnt(3)" ::: "memory");
    else        asm volatile("s_waitcnt vmcnt(0)" ::: "memory");
    __builtin_amdgcn_s_barrier();
    __builtin_amdgcn_sched_barrier(0);
    if (s + 2 < 32)
      projo_stage(X, W, mt, nt, (s + 2) * 32, smem + ((s + 2) % 3) * BUFB, wid, lane);

    unsigned char* Al = smem + (s % 3) * BUFB;
    unsigned char* Bl = Al + 8192;
    bf16x8 af[4], bfr[2];
#pragma unroll
    for (int mi = 0; mi < 4; ++mi)
      af[mi] = *(const bf16x8*)(Al + (wm * 64 + mi * 16 + l15) * 64 + l4 * 16);
#pragma unroll
    for (int nj = 0; nj < 2; ++nj)
      bfr[nj] = *(const bf16x8*)(Bl + (wn * 32 + nj * 16 + l15) * 64 + l4 * 16);
    __builtin_amdgcn_s_setprio(1);
#pragma unroll
    for (int mi = 0; mi < 4; ++mi)
#pragma unroll
      for (int nj = 0; nj < 2; ++nj)
        acc[mi][nj] = __builtin_amdgcn_mfma_f32_16x16x32_bf16(af[mi], bfr[nj], acc[mi][nj], 0, 0, 0);
    __builtin_amdgcn_s_setprio(0);
  }

  const int row0 = mt * 128 + wm * 64;
  const int col0 = nt * 64 + wn * 32;
#pragma unroll
  for (int nj = 0; nj < 2; ++nj) {
    const int col = col0 + nj * 16 + l15;
    const float bv = bvv[nj];
#pragma unroll
    for (int mi = 0; mi < 4; ++mi)
#pragma unroll
      for (int r = 0; r < 4; ++r)
        outf[(size_t)(row0 + mi * 16 + l4 * 4 + r) * CH + col] = acc[mi][nj][r] + bv;
  }
}

// ---------------- flash attention: in-block split-K, 8 waves (R7 verbatim) --
__device__ __forceinline__ void stage_kv(
    const unsigned short* __restrict__ Kb, const unsigned short* __restrict__ Vb,
    int j0, unsigned char* buf, int ws3, int lane) {
#pragma unroll
  for (int is = 0; is < 2; ++is) {
    const int p = ws3 * 2048 + is * 1024 + lane * 16;
    const int row = p >> 7;
    const int sw = ((p & 127) ^ ((row & 7) << 4)) >> 1;
    gload16(Kb + (size_t)(j0 + row) * HD + sw, buf + ws3 * 2048 + is * 1024);
    gload16(Vb + (size_t)row * SEQ + j0 + sw, buf + 8192 + ws3 * 2048 + is * 1024);
  }
}

__global__ __launch_bounds__(512, 4) void attn_kernel(
    const unsigned short* __restrict__ Qh, const unsigned short* __restrict__ Kh,
    const unsigned short* __restrict__ Vt, unsigned short* __restrict__ AO) {
  __shared__ __align__(16) unsigned char smem[81920];
  const int tid = threadIdx.x, wid = tid >> 6, lane = tid & 63;
  const int l31 = lane & 31, h = lane >> 5;
  const int grp = wid >> 2, wq = wid & 3;
  const int bid = blockIdx.x;
  const int swz = (bid & 7) * 64 + (bid >> 3);  // bijective: 512 % 8 == 0
  const int qt = swz & 15, bh = swz >> 4;

  const unsigned short* Qb = Qh + ((size_t)bh * SEQ + qt * 128) * HD;
  const unsigned short* Kb = Kh + (size_t)bh * SEQ * HD;
  const unsigned short* Vb = Vt + (size_t)bh * HD * SEQ;
  unsigned char* kvb = smem + grp * 32768;
  unsigned char* Qreg = smem + 65536;
  const int jbase = grp * 16;

#pragma unroll
  for (int is = 0; is < 4; ++is) {
    const int p = wq * 4096 + is * 1024 + lane * 16;
    const int row = p >> 7;
    const int sw = ((p & 127) ^ ((row & 7) << 4)) >> 1;
    gload16(Qb + (size_t)row * HD + sw, Qreg + wq * 4096 + is * 1024);
  }
  stage_kv(Kb, Vb, jbase * 64, kvb, wq, lane);
  asm volatile("s_waitcnt vmcnt(4)" ::: "memory");

  bf16x8 qf[4];
  const int qrow = wq * 32 + l31;
#pragma unroll
  for (int ks = 0; ks < 4; ++ks)
    qf[ks] = *(const bf16x8*)(Qreg + qrow * 128 +
                              ((ks * 32 + h * 16) ^ ((qrow & 7) << 4)));

  stage_kv(Kb, Vb, (jbase + 1) * 64, kvb + 16384, wq, lane);

  f32x16 O[2] = {};
  float m = -1e30f, l = 0.f;

  for (int it = 0; it < 16; ++it) {
    if (it < 15) asm volatile("s_waitcnt vmcnt(4)" ::: "memory");
    else         asm volatile("s_waitcnt vmcnt(0)" ::: "memory");
    __builtin_amdgcn_s_barrier();
    __builtin_amdgcn_sched_barrier(0);

    unsigned char* Kc = kvb + ((it & 1) << 14);
    unsigned char* Vc = Kc + 8192;

    f32x16 st[2] = {};
    __builtin_amdgcn_s_setprio(1);
#pragma unroll
    for (int kb = 0; kb < 2; ++kb) {
#pragma unroll
      for (int ks = 0; ks < 4; ++ks) {
        const int krow = kb * 32 + l31;
        const bf16x8 kf = *(const bf16x8*)(Kc + krow * 128 +
                                           ((ks * 32 + h * 16) ^ ((krow & 7) << 4)));
        st[kb] = __builtin_amdgcn_mfma_f32_32x32x16_bf16(kf, qf[ks], st[kb], 0, 0, 0);
      }
    }
    __builtin_amdgcn_s_setprio(0);

    float t[8];
#pragma unroll
    for (int i = 0; i < 8; ++i)
      t[i] = fmaxf(fmaxf(st[0][i], st[0][i + 8]), fmaxf(st[1][i], st[1][i + 8]));
#pragma unroll
    for (int i = 0; i < 4; ++i) t[i] = fmaxf(t[i], t[i + 4]);
    float pmax = fmaxf(fmaxf(t[0], t[1]), fmaxf(t[2], t[3]));
    pmax = fmaxf(pmax, __shfl_xor(pmax, 32));
    if (__any(pmax > m + 8.f)) {
      const float mnew = fmaxf(m, pmax);
      const float alpha = fexp2(m - mnew);
#pragma unroll
      for (int r = 0; r < 16; ++r) {
        const int qO = (r & 3) + 8 * (r >> 2) + 4 * h;
        const float aO = __shfl(alpha, qO);
        O[0][r] *= aO;
        O[1][r] *= aO;
      }
      l *= alpha;
      m = mnew;
    }
#pragma unroll
    for (int kb = 0; kb < 2; ++kb)
#pragma unroll
      for (int i = 0; i < 16; ++i) st[kb][i] = fexp2(st[kb][i] - m);
    float s[8];
#pragma unroll
    for (int i = 0; i < 8; ++i)
      s[i] = (st[0][i] + st[0][i + 8]) + (st[1][i] + st[1][i + 8]);
#pragma unroll
    for (int i = 0; i < 4; ++i) s[i] += s[i + 4];
    float rs = (s[0] + s[1]) + (s[2] + s[3]);
    rs += __shfl_xor(rs, 32);
    l += rs;

    unsigned int pk[2][8];
#pragma unroll
    for (int kb = 0; kb < 2; ++kb)
#pragma unroll
      for (int j = 0; j < 8; ++j)
        pk[kb][j] = cvtpk(st[kb][2 * j], st[kb][2 * j + 1]);

    __builtin_amdgcn_s_setprio(1);
#pragma unroll
    for (int kk = 0; kk < 4; ++kk) {
      const int kb = kk >> 1, j0 = (kk & 1) * 4;
      const unsigned int p0 = pk[kb][j0 + 0], p1 = pk[kb][j0 + 1];
      const unsigned int p2 = pk[kb][j0 + 2], p3 = pk[kb][j0 + 3];
      const unsigned int u0 = h ? p0 : p2;
      const unsigned int u1 = h ? p1 : p3;
      const unsigned int su0 = __shfl_xor(u0, 32);
      const unsigned int su1 = __shfl_xor(u1, 32);
      const unsigned int d0 = h ? su0 : p0;
      const unsigned int d1 = h ? su1 : p1;
      const unsigned int d2 = h ? p2 : su0;
      const unsigned int d3 = h ? p3 : su1;
      uint4 aw = make_uint4(d0, d1, d2, d3);
      const bf16x8 af = *(const bf16x8*)&aw;
#pragma unroll
      for (int db = 0; db < 2; ++db) {
        const int vrow = db * 32 + l31;
        const bf16x8 vf = *(const bf16x8*)(Vc + vrow * 128 +
                                           ((kk * 32 + h * 16) ^ ((vrow & 7) << 4)));
        O[db] = __builtin_amdgcn_mfma_f32_32x32x16_bf16(af, vf, O[db], 0, 0, 0);
      }
    }
    __builtin_amdgcn_s_setprio(0);

    __builtin_amdgcn_s_barrier();
    if (it + 2 < 16)
      stage_kv(Kb, Vb, (jbase + it + 2) * 64, Kc, wq, lane);
  }

  float2* slotO = (float2*)(smem + wq * 8960);
  float2* slotML = (float2*)(smem + wq * 8960 + 8704);
  if (grp == 1) {
    float2* dst = slotO + lane * 17;
#pragma unroll
    for (int i = 0; i < 8; ++i) dst[i] = make_float2(O[0][2 * i], O[0][2 * i + 1]);
#pragma unroll
    for (int i = 0; i < 8; ++i) dst[8 + i] = make_float2(O[1][2 * i], O[1][2 * i + 1]);
    if (h == 0) slotML[l31] = make_float2(m, l);
  }
  __builtin_amdgcn_s_barrier();
  if (grp == 0) {
    const float* src = (const float*)(slotO + lane * 17);
    const float2 ml1 = slotML[l31];
    const float mm = fmaxf(m, ml1.x);
    const float a0 = fexp2(m - mm), a1 = fexp2(ml1.x - mm);
    const float inv = 1.f / (a0 * l + a1 * ml1.y);
    const float w0 = a0 * inv, w1 = a1 * inv;
    const int b = bh >> 4, hh = bh & 15;
#pragma unroll
    for (int r = 0; r < 16; ++r) {
      const int qO = (r & 3) + 8 * (r >> 2) + 4 * h;
      const float s0 = __shfl(w0, qO), s1 = __shfl(w1, qO);
      const int n = qt * 128 + wq * 32 + qO;
      const size_t base = ((size_t)(b * SEQ + n)) * CH + hh * HD;
      AO[base + l31] = f2b(O[0][r] * s0 + src[r] * s1);
      AO[base + 32 + l31] = f2b(O[1][r] * s0 + src[16 + r] * s1);
    }
  }
}

extern "C" void kernel_launch(void* const* d_in, const int* in_sizes, int n_in,
                              void* d_out, int out_size, void* d_ws, size_t ws_size,
                              hipStream_t stream) {
  (void)in_sizes; (void)n_in; (void)out_size; (void)ws_size;
  const float* q  = (const float*)d_in[0];
  const float* k  = (const float*)d_in[1];
  const float* v  = (const float*)d_in[2];
  const float* wq = (const float*)d_in[3];
  const float* bq = (const float*)d_in[4];
  const float* wk = (const float*)d_in[5];
  const float* bk = (const float*)d_in[6];
  const float* wv = (const float*)d_in[7];
  const float* bv = (const float*)d_in[8];
  const float* wo = (const float*)d_in[9];
  const float* bo = (const float*)d_in[10];

  unsigned char* ws = (unsigned char*)d_ws;
  const size_t MB8 = 8u << 20;
  unsigned short* AO  = (unsigned short*)(ws + 0 * MB8);
  unsigned short* Vt  = (unsigned short*)(ws + 1 * MB8);
  unsigned short* wqb = (unsigned short*)(ws + 3 * MB8);
  unsigned short* wkb = (unsigned short*)(ws + 3 * MB8 + 1 * 2097152);
  unsigned short* wvb = (unsigned short*)(ws + 3 * MB8 + 2 * 2097152);
  unsigned short* wob = (unsigned short*)(ws + 3 * MB8 + 3 * 2097152);
  unsigned short* Qh  = (unsigned short*)(ws + 4 * MB8);
  unsigned short* Kh  = (unsigned short*)(ws + 5 * MB8);
  float* out = (float*)d_out;

  CvtArgs ca;
  ca.src[0] = wq; ca.dst[0] = wqb; ca.n4[0] = CH * CH / 4;
  ca.src[1] = wk; ca.dst[1] = wkb; ca.n4[1] = CH * CH / 4;
  ca.src[2] = wv; ca.dst[2] = wvb; ca.n4[2] = CH * CH / 4;
  ca.src[3] = wo; ca.dst[3] = wob; ca.n4[3] = CH * CH / 4;
  cvt_kernel<<<dim3(512, 4), 256, 0, stream>>>(ca);

  Proj3Args p3;
  p3.X[0] = q; p3.W[0] = wqb; p3.bias[0] = bq; p3.outb[0] = Qh; p3.mode[0] = 0;
  p3.X[1] = k; p3.W[1] = wkb; p3.bias[1] = bk; p3.outb[1] = Kh; p3.mode[1] = 1;
  p3.X[2] = v; p3.W[2] = wvb; p3.bias[2] = bv; p3.outb[2] = Vt; p3.mode[2] = 3;
  proj3_kernel<<<dim3(32, 8, 3), 256, 0, stream>>>(p3);

  attn_kernel<<<dim3(512), 512, 0, stream>>>(Qh, Kh, Vt, AO);

  projo_kernel<<<dim3(32, 16), 256, 0, stream>>>(AO, wob, bo, out);
}